// Round 1
// baseline (382.463 us; speedup 1.0000x reference)
//
#include <hip/hip_runtime.h>

// Reduction scatter slots: spread same-address atomic contention.
#define SLOTS 256

// One 64-lane wave per point. Lane k (k<K) handles neighbor k.
// v/vn: (NP, K, 3) fp32 -> lane k reads 3 consecutive floats at stride 12B
// across lanes (coalesced at cache-line granularity). sr: (NP, K) perfectly
// coalesced. Point coords are wave-uniform loads (cache broadcast).
__global__ __launch_bounds__(256) void sdf_main(
    const float* __restrict__ points,
    const float* __restrict__ v,
    const float* __restrict__ vn,
    const float* __restrict__ sr,
    float* __restrict__ ws,
    int NP, int K, int P)
{
    const int wave = blockIdx.x * 4 + (threadIdx.x >> 6);
    const int lane = threadIdx.x & 63;
    if (wave >= NP) return;

    // point coords (uniform within wave; L1 broadcast)
    const float px = points[wave * 3 + 0];
    const float py = points[wave * 3 + 1];
    const float pz = points[wave * 3 + 2];

    float num = 0.0f, den = 0.0f;
    if (lane < K) {
        const int base = (wave * K + lane) * 3;
        const float vx = v[base + 0];
        const float vy = v[base + 1];
        const float vz = v[base + 2];
        const float nx = vn[base + 0];
        const float ny = vn[base + 1];
        const float nz = vn[base + 2];
        const float s  = sr[wave * K + lane];

        const float dx = px - vx;
        const float dy = py - vy;
        const float dz = pz - vz;
        const float d2 = dx * dx + dy * dy + dz * dz;
        const float w  = 1.0f - d2 / s;
        const float w2 = w * w;
        const float phi = (d2 < s) ? (w2 * w2) : 1e-18f;
        const float dot = nx * dx + ny * dy + nz * dz;
        num = phi * dot;
        den = phi;
    }

    // 64-lane butterfly reduction
    #pragma unroll
    for (int off = 32; off >= 1; off >>= 1) {
        num += __shfl_xor(num, off, 64);
        den += __shfl_xor(den, off, 64);
    }

    if (lane == 0) {
        const float sdf = num / den;
        const int n = wave / P;                 // batch index
        const int slot = wave & (SLOTS - 1);    // scatter contention
        atomicAdd(&ws[slot * 2 + n], sdf * sdf);
    }
}

// Single-block final reduction: 512 threads; threads [0,256) reduce n=0,
// [256,512) reduce n=1.
__global__ __launch_bounds__(512) void sdf_reduce(
    const float* __restrict__ ws, float* __restrict__ out, int N)
{
    __shared__ float sm[2 * SLOTS];
    const int tid  = threadIdx.x;
    const int n    = tid >> 8;
    const int slot = tid & (SLOTS - 1);
    sm[tid] = (n < N) ? ws[slot * 2 + n] : 0.0f;
    __syncthreads();
    #pragma unroll
    for (int s = SLOTS / 2; s >= 1; s >>= 1) {
        if (slot < s) sm[tid] += sm[tid + s];
        __syncthreads();
    }
    if (slot == 0 && n < N) out[n] = sm[tid];
}

extern "C" void kernel_launch(void* const* d_in, const int* in_sizes, int n_in,
                              void* d_out, int out_size, void* d_ws, size_t ws_size,
                              hipStream_t stream) {
    const float* points = (const float*)d_in[0];
    const float* v      = (const float*)d_in[1];
    const float* vn     = (const float*)d_in[2];
    const float* sr     = (const float*)d_in[3];
    float* out = (float*)d_out;
    float* ws  = (float*)d_ws;

    const int NP = in_sizes[0] / 3;        // N*P total points (200000)
    const int K  = in_sizes[3] / NP;       // 60
    const int N  = out_size;               // 2
    const int P  = NP / N;                 // 100000

    // ws is re-poisoned to 0xAA before every launch; zero the slots we use.
    hipMemsetAsync(ws, 0, SLOTS * 2 * sizeof(float), stream);

    const int waves_needed = NP;
    const int blocks = (waves_needed + 3) / 4;   // 4 waves (256 thr) per block
    sdf_main<<<blocks, 256, 0, stream>>>(points, v, vn, sr, ws, NP, K, P);
    sdf_reduce<<<1, 2 * SLOTS, 0, stream>>>(ws, out, N);
}

// Round 2
// 327.028 us; speedup vs baseline: 1.1695x; 1.1695x over previous
//
#include <hip/hip_runtime.h>

// Scatter slots for the per-wave atomic partial sums. Each slot gets its own
// 64-B cache line (stride 16 floats) so L2 atomic RMWs don't serialize on a
// handful of lines.
#define RED_THREADS 512

// One 64-lane wave per point (4 waves / 256-thread block).
// Per point: v row = 180 floats (720 B, 16-B aligned), vn row = 180 floats,
// sr row = 60 floats (240 B, 16-B aligned).
// Stage rows into LDS with float4 loads (full memory-level parallelism,
// perfectly coalesced), then lane k<60 reads its 7 scalars from LDS.
__global__ __launch_bounds__(256) void sdf_main(
    const float* __restrict__ points,
    const float* __restrict__ v,
    const float* __restrict__ vn,
    const float* __restrict__ sr,
    float* __restrict__ ws,
    int NP, int P, int slots, int slotStride)
{
    constexpr int K = 60;
    __shared__ float4 sv[4][45];
    __shared__ float4 sn[4][45];
    __shared__ float4 ss[4][15];

    const int w     = threadIdx.x >> 6;
    const int lane  = threadIdx.x & 63;
    const int point = blockIdx.x * 4 + w;
    const bool active = point < NP;

    float px = 0.f, py = 0.f, pz = 0.f;
    if (active) {
        // Issue all global loads up front — 3 independent dwordx4 per thread.
        const float4* v4 = (const float4*)(v  + (size_t)point * (K * 3));
        const float4* n4 = (const float4*)(vn + (size_t)point * (K * 3));
        const float4* s4 = (const float4*)(sr + (size_t)point * K);
        float4 rv, rn, rs;
        if (lane < 45) rv = v4[lane];
        if (lane < 45) rn = n4[lane];
        if (lane < 15) rs = s4[lane];
        // wave-uniform point coords -> scalar loads, L1 broadcast
        px = points[point * 3 + 0];
        py = points[point * 3 + 1];
        pz = points[point * 3 + 2];
        if (lane < 45) sv[w][lane] = rv;
        if (lane < 45) sn[w][lane] = rn;
        if (lane < 15) ss[w][lane] = rs;
    }
    __syncthreads();

    float num = 0.f, den = 0.f;
    if (active && lane < K) {
        const float* vf = (const float*)sv[w];
        const float* nf = (const float*)sn[w];
        const float* sf = (const float*)ss[w];
        const float vx = vf[3 * lane + 0];
        const float vy = vf[3 * lane + 1];
        const float vz = vf[3 * lane + 2];
        const float nx = nf[3 * lane + 0];
        const float ny = nf[3 * lane + 1];
        const float nz = nf[3 * lane + 2];
        const float s  = sf[lane];

        const float dx = px - vx;
        const float dy = py - vy;
        const float dz = pz - vz;
        const float d2 = dx * dx + dy * dy + dz * dz;
        const float wq = 1.0f - d2 / s;
        const float w2 = wq * wq;
        const float phi = (d2 < s) ? (w2 * w2) : 1e-18f;
        const float dot = nx * dx + ny * dy + nz * dz;
        num = phi * dot;
        den = phi;
    }

    // 64-lane butterfly reduction
    #pragma unroll
    for (int off = 32; off >= 1; off >>= 1) {
        num += __shfl_xor(num, off, 64);
        den += __shfl_xor(den, off, 64);
    }

    if (active && lane == 0) {
        const float sdf = num / den;
        const int n    = point / P;
        const int slot = point & (slots - 1);
        atomicAdd(&ws[slot * slotStride + n], sdf * sdf);
    }
}

// Single-block final reduction over `slots` partial sums per batch index.
__global__ __launch_bounds__(RED_THREADS) void sdf_reduce(
    const float* __restrict__ ws, float* __restrict__ out,
    int N, int slots, int slotStride)
{
    __shared__ float sm0[RED_THREADS];
    __shared__ float sm1[RED_THREADS];
    const int tid = threadIdx.x;
    float a = 0.f, b = 0.f;
    for (int s = tid; s < slots; s += RED_THREADS) {
        a += ws[s * slotStride + 0];
        if (N > 1) b += ws[s * slotStride + 1];
    }
    sm0[tid] = a;
    sm1[tid] = b;
    __syncthreads();
    #pragma unroll
    for (int s = RED_THREADS / 2; s >= 1; s >>= 1) {
        if (tid < s) {
            sm0[tid] += sm0[tid + s];
            sm1[tid] += sm1[tid + s];
        }
        __syncthreads();
    }
    if (tid == 0) {
        out[0] = sm0[0];
        if (N > 1) out[1] = sm1[0];
    }
}

extern "C" void kernel_launch(void* const* d_in, const int* in_sizes, int n_in,
                              void* d_out, int out_size, void* d_ws, size_t ws_size,
                              hipStream_t stream) {
    const float* points = (const float*)d_in[0];
    const float* v      = (const float*)d_in[1];
    const float* vn     = (const float*)d_in[2];
    const float* sr     = (const float*)d_in[3];
    float* out = (float*)d_out;
    float* ws  = (float*)d_ws;

    const int NP = in_sizes[0] / 3;        // N*P total points (200000)
    const int N  = out_size;               // 2
    const int P  = NP / N;                 // 100000

    // Pick atomic-scatter geometry based on available workspace.
    int slots = 512, slotStride = 16;      // 32 KiB: one cache line per slot
    if (ws_size < (size_t)(slots * slotStride * sizeof(float))) {
        slots = 256; slotStride = 2;       // 2 KiB fallback
    }

    hipMemsetAsync(ws, 0, (size_t)slots * slotStride * sizeof(float), stream);

    const int blocks = (NP + 3) / 4;       // 4 waves (256 thr) per block
    sdf_main<<<blocks, 256, 0, stream>>>(points, v, vn, sr, ws, NP, P,
                                         slots, slotStride);
    sdf_reduce<<<1, RED_THREADS, 0, stream>>>(ws, out, N, slots, slotStride);
}